// Round 4
// baseline (213.049 us; speedup 1.0000x reference)
//
#include <hip/hip_runtime.h>

#define N     4096
#define FIN   256
#define CC    256   // HEADS * F_OUT
#define HEADS 4
#define FOUT  64

typedef __attribute__((ext_vector_type(8))) short bf16x8;
typedef __attribute__((ext_vector_type(4))) float f32x4;

// float -> bf16 (round-nearest-even)
__device__ inline short f2bf(float f) {
    unsigned u = __builtin_bit_cast(unsigned, f);
    unsigned r = u + 0x7fffu + ((u >> 16) & 1u);
    return (short)(r >> 16);
}

// Kernel 1, fused:
//   blocks [0,256):   h = x@W via MFMA (one head x 64 n-rows), writing
//                     hF in FRAGMENT ORDER (k2's B-frags become coalesced
//                     1KB loads) + e1T/e2T wave-reduced.
//   blocks [256,768): adj -> bitmask adjb (ballot), + zero d_out.
__global__ __launch_bounds__(256) void gat_k1(const float* __restrict__ x,
                                              const float* __restrict__ W,
                                              const float* __restrict__ a,
                                              const int* __restrict__ adj,
                                              short* __restrict__ hF,
                                              float* __restrict__ e1T,
                                              float* __restrict__ e2T,
                                              unsigned* __restrict__ adjb,
                                              float* __restrict__ out) {
    __shared__ __align__(16) short xs[64][FIN + 8];    // x tile bf16, 33.8 KB
    __shared__ __align__(16) short wts[64][FIN + 8];   // W^T slice,  33.8 KB
    __shared__ __align__(16) short hbuf[64][72];       // transpose,   9 KB
    const int t   = threadIdx.x;
    const int bid = blockIdx.x;

    if (bid >= 256) {
        // ---- adj bitmask + out zero ----
        const int ab = bid - 256;                      // 0..511
        if (ab < 256) ((float4*)out)[ab * 256 + t] = make_float4(0.f, 0.f, 0.f, 0.f);
        const int lane = t & 63;
        const int w    = t >> 6;
        #pragma unroll
        for (int rr = 0; rr < 2; ++rr) {
            const int row = ab * 8 + w * 2 + rr;
            const int* arow = adj + (size_t)row * N;
            unsigned long long* drow = (unsigned long long*)(adjb + (size_t)row * 128);
            #pragma unroll 4
            for (int it = 0; it < 64; ++it) {
                const unsigned long long mk = __ballot(arow[it * 64 + lane] != 0);
                if (lane == 0) drow[it] = mk;          // bit b = adj[row][it*64+b]
            }
        }
        return;
    }

    // ---- GEMM block ----
    const int hd = bid >> 6;
    const int n0 = (bid & 63) * 64;
    const int c0 = hd * 64;

    {   // stage x rows n0..n0+63 as bf16
        const float4* xsrc = (const float4*)(x + (size_t)n0 * FIN);
        #pragma unroll
        for (int it = 0; it < 16; ++it) {
            const int fi = it * 256 + t;
            const float4 v = xsrc[fi];
            short4 o;
            o.x = f2bf(v.x); o.y = f2bf(v.y); o.z = f2bf(v.z); o.w = f2bf(v.w);
            *(short4*)&xs[fi >> 6][(fi & 63) * 4] = o;
        }
    }
    {   // stage W^T column slice
        const int c  = t & 63;
        const int k4 = (t >> 6) * 4;
        #pragma unroll
        for (int it = 0; it < 16; ++it) {
            const int k = it * 16 + k4;
            short4 pk;
            pk.x = f2bf(W[(k + 0) * CC + c0 + c]);
            pk.y = f2bf(W[(k + 1) * CC + c0 + c]);
            pk.z = f2bf(W[(k + 2) * CC + c0 + c]);
            pk.w = f2bf(W[(k + 3) * CC + c0 + c]);
            *(short4*)&wts[c][k] = pk;
        }
    }
    __syncthreads();

    const int lane = t & 63;
    const int w    = t >> 6;
    const int m    = lane & 15;
    const int q    = lane >> 4;

    f32x4 acc[4];
    #pragma unroll
    for (int ct = 0; ct < 4; ++ct) acc[ct] = (f32x4){0.f, 0.f, 0.f, 0.f};

    #pragma unroll
    for (int ks = 0; ks < 8; ++ks) {
        const bf16x8 af = *(const bf16x8*)&xs[w * 16 + m][ks * 32 + q * 8];
        #pragma unroll
        for (int ct = 0; ct < 4; ++ct) {
            const bf16x8 bf_ = *(const bf16x8*)&wts[ct * 16 + m][ks * 32 + q * 8];
            acc[ct] = __builtin_amdgcn_mfma_f32_16x16x32_bf16(af, bf_, acc[ct], 0, 0, 0);
        }
    }

    // e1/e2 from fp32 acc
    const float a1v[4] = {a[m], a[16 + m], a[32 + m], a[48 + m]};
    const float a2v[4] = {a[64 + m], a[80 + m], a[96 + m], a[112 + m]};
    #pragma unroll
    for (int r = 0; r < 4; ++r) {
        float s1 = 0.f, s2 = 0.f;
        #pragma unroll
        for (int ct = 0; ct < 4; ++ct) {
            s1 = fmaf(acc[ct][r], a1v[ct], s1);
            s2 = fmaf(acc[ct][r], a2v[ct], s2);
        }
        #pragma unroll
        for (int sh = 1; sh < 16; sh <<= 1) {
            s1 += __shfl_xor(s1, sh, 64);
            s2 += __shfl_xor(s2, sh, 64);
        }
        if (m == 0) {
            const int n = n0 + w * 16 + q * 4 + r;
            e1T[hd * N + n] = s1;
            e2T[hd * N + n] = s2;
        }
    }

    // transpose h tile to [c][n-local]
    #pragma unroll
    for (int ct = 0; ct < 4; ++ct)
        #pragma unroll
        for (int r = 0; r < 4; ++r)
            hbuf[ct * 16 + m][w * 16 + q * 4 + r] = f2bf(acc[ct][r]);
    __syncthreads();

    // write hF in fragment order: frag(jc, ft) lane lp holds
    // h[f=ft*16+(lp&15)][j = jc*32 + (lp>>4)*8 + 0..7]
    {
        const int lp = t & 63;
        const int ft = t >> 6;
        const int mm = lp & 15;
        const int qq = lp >> 4;
        #pragma unroll
        for (int c2 = 0; c2 < 2; ++c2) {
            const bf16x8 hv = *(const bf16x8*)&hbuf[ft * 16 + mm][c2 * 32 + qq * 8];
            const size_t jc = (size_t)(n0 >> 5) + c2;
            *(bf16x8*)(hF + ((((size_t)hd * 128 + jc) * 4 + ft) * 64 + lp) * 8) = hv;
        }
    }
}

// Kernel 2: masked-softmax aggregation via MFMA, scatter-free.
// One (i-tile, head) per block; 8 waves = 8 j-stripes. adj bits + e2 staged
// in LDS; hF B-frags are coalesced 1KB dwordx4 loads. Grid 1024 = 4 blk/CU.
__global__ __launch_bounds__(512, 8) void gat_k2(const short* __restrict__ hF,
                                                 const unsigned* __restrict__ adjb,
                                                 const float* __restrict__ e1T,
                                                 const float* __restrict__ e2T,
                                                 float* __restrict__ out) {
    __shared__ float obuf[16][64];            // 4 KB
    __shared__ float zbuf[8][16];
    __shared__ __align__(16) float e2lds[N];  // 16 KB
    __shared__ unsigned adjlds[16 * 129];     // 8.25 KB, +1 pad breaks bank alias
    const int t    = threadIdx.x;
    const int lane = t & 63;
    const int g    = t >> 6;
    const int bid  = blockIdx.x;
    const int hd   = (bid >> 3) & 3;
    const int it   = (bid & 7) | ((bid >> 5) << 3);   // XCD-affine i-tile
    const int i0   = it * 16;
    const int m    = lane & 15;
    const int q    = lane >> 4;

    {   float* ob = &obuf[0][0]; ob[t] = 0.f; ob[t + 512] = 0.f; }
    {   // stage e2 row (this head, all j)
        const float4* src = (const float4*)(e2T + (size_t)hd * N);
        float4* dst = (float4*)e2lds;
        dst[t] = src[t]; dst[t + 512] = src[t + 512];
    }
    {   // stage adj bits for 16 i-rows (512B data per row, 129-word pitch)
        const unsigned* src = adjb + (size_t)i0 * 128;
        #pragma unroll
        for (int r = 0; r < 4; ++r) {
            const int idx = t + r * 512;
            adjlds[(idx >> 7) * 129 + (idx & 127)] = src[idx];
        }
    }
    __syncthreads();

    const float e1v = e1T[hd * N + i0 + m];

    f32x4 accf[4];
    #pragma unroll
    for (int ft = 0; ft < 4; ++ft) accf[ft] = (f32x4){0.f, 0.f, 0.f, 0.f};
    float zacc = 0.f;

    // frag base: chunk jc = g + step*8; layout hF[hd][jc][ft][lane][8]
    const short* hbase = hF + (((size_t)hd * 128 + g) * 4 * 64 + lane) * 8;
    const unsigned char* abyte = ((const unsigned char*)adjlds) + m * 516 + g * 4 + q;

    for (int step = 0; step < 16; ++step) {
        const short* hstep = hbase + (size_t)step * 16384;   // 8 chunks * 2048
        const bf16x8 b0 = *(const bf16x8*)(hstep);
        const bf16x8 b1 = *(const bf16x8*)(hstep + 512);
        const bf16x8 b2 = *(const bf16x8*)(hstep + 1024);
        const bf16x8 b3 = *(const bf16x8*)(hstep + 1536);

        const int jbase = g * 32 + step * 256 + q * 8;
        const float4 ce0 = *(const float4*)&e2lds[jbase];
        const float4 ce1 = *(const float4*)&e2lds[jbase + 4];
        const unsigned bits = (unsigned)abyte[step * 32];

        const float ev[8] = {ce0.x, ce0.y, ce0.z, ce0.w, ce1.x, ce1.y, ce1.z, ce1.w};
        bf16x8 afrag;
        #pragma unroll
        for (int jj = 0; jj < 8; ++jj) {
            float e = e1v + ev[jj];
            e = fmaxf(e, 0.2f * e);                          // leaky relu
            const float wv = ((bits >> jj) & 1u) ? __expf(e) : 0.f;
            zacc += wv;
            afrag[jj] = f2bf(wv);
        }

        accf[0] = __builtin_amdgcn_mfma_f32_16x16x32_bf16(afrag, b0, accf[0], 0, 0, 0);
        accf[1] = __builtin_amdgcn_mfma_f32_16x16x32_bf16(afrag, b1, accf[1], 0, 0, 0);
        accf[2] = __builtin_amdgcn_mfma_f32_16x16x32_bf16(afrag, b2, accf[2], 0, 0, 0);
        accf[3] = __builtin_amdgcn_mfma_f32_16x16x32_bf16(afrag, b3, accf[3], 0, 0, 0);
    }

    // Z: stripe partial per row m
    zacc += __shfl_xor(zacc, 16, 64);
    zacc += __shfl_xor(zacc, 32, 64);
    if (lane < 16) zbuf[g][lane] = zacc;

    // numerator: C layout row=q*4+r, col=ft*16+m
    #pragma unroll
    for (int ft = 0; ft < 4; ++ft)
        #pragma unroll
        for (int r = 0; r < 4; ++r)
            atomicAdd(&obuf[q * 4 + r][ft * 16 + m], accf[ft][r]);
    __syncthreads();

    #pragma unroll
    for (int rep = 0; rep < 2; ++rep) {
        const int idx = t + rep * 512;
        const int ii  = idx >> 6;
        const int ff  = idx & 63;
        float Z = 0.f;
        #pragma unroll
        for (int gg = 0; gg < 8; ++gg) Z += zbuf[gg][ii];
        atomicAdd(&out[(size_t)(i0 + ii) * FOUT + ff], 0.25f * obuf[ii][ff] / Z);
    }
}

extern "C" void kernel_launch(void* const* d_in, const int* in_sizes, int n_in,
                              void* d_out, int out_size, void* d_ws, size_t ws_size,
                              hipStream_t stream) {
    const float* x   = (const float*)d_in[0];
    const int*   adj = (const int*)d_in[1];
    const float* W   = (const float*)d_in[2];
    const float* a   = (const float*)d_in[3];
    float* out = (float*)d_out;

    short*    hF   = (short*)d_ws;                           // 2 MB
    float*    e1T  = (float*)(hF + (size_t)HEADS * FOUT * N);
    float*    e2T  = e1T + (size_t)HEADS * N;
    unsigned* adjb = (unsigned*)(e2T + (size_t)HEADS * N);   // 2 MB

    gat_k1<<<768, 256, 0, stream>>>(x, W, a, adj, hF, e1T, e2T, adjb, out);
    gat_k2<<<1024, 512, 0, stream>>>(hF, adjb, e1T, e2T, out);
}

// Round 5
// 171.225 us; speedup vs baseline: 1.2443x; 1.2443x over previous
//
#include <hip/hip_runtime.h>

#define N     4096
#define FIN   256
#define CC    256   // HEADS * F_OUT
#define HEADS 4
#define FOUT  64
#define XPITCH 266  // FIN+10 shorts = 133 dwords (odd) -> conflict-free
#define HPITCH 74   // 37 dwords (odd)

typedef __attribute__((ext_vector_type(8))) short bf16x8;
typedef __attribute__((ext_vector_type(4))) float f32x4;

// float -> bf16 (round-nearest-even)
__device__ inline short f2bf(float f) {
    unsigned u = __builtin_bit_cast(unsigned, f);
    unsigned r = u + 0x7fffu + ((u >> 16) & 1u);
    return (short)(r >> 16);
}

// Kernel 1, fused:
//   blocks [0,256):    h = x@W via MFMA (one head x 64 n-rows) -> hF in
//                      fragment order + e1T/e2T; also zeroes d_out.
//   blocks [256,1280): adj -> bitmask adjb. One row per wave. Batched int4
//                      loads (4 in flight, NO convergent op between them),
//                      then nibble/byte/hword shfl_xor packing -> 1 dword
//                      per 8 lanes, little-endian bit order.
__global__ __launch_bounds__(256) void gat_k1(const float* __restrict__ x,
                                              const float* __restrict__ W,
                                              const float* __restrict__ a,
                                              const int* __restrict__ adj,
                                              short* __restrict__ hF,
                                              float* __restrict__ e1T,
                                              float* __restrict__ e2T,
                                              unsigned* __restrict__ adjb,
                                              float* __restrict__ out) {
    __shared__ __align__(16) short xs[64][XPITCH];    // 34.0 KB
    __shared__ __align__(16) short wts[64][XPITCH];   // 34.0 KB
    __shared__ __align__(16) short hbuf[64][HPITCH];  //  9.5 KB
    const int t    = threadIdx.x;
    const int bid  = blockIdx.x;
    const int lane = t & 63;
    const int w    = t >> 6;

    if (bid >= 256) {
        // ---- adj bitmask pack ----
        const int row = (bid - 256) * 4 + w;
        const int4* arow4 = (const int4*)(adj + (size_t)row * N);
        unsigned* drow = adjb + (size_t)row * 128;
        #pragma unroll
        for (int p4 = 0; p4 < 4; ++p4) {
            int4 ca[4];
            #pragma unroll
            for (int k = 0; k < 4; ++k)
                ca[k] = arow4[(p4 * 4 + k) * 64 + lane];   // batched, coalesced 1KB
            #pragma unroll
            for (int k = 0; k < 4; ++k) {
                const int4 v = ca[k];
                unsigned n = (v.x != 0 ? 1u : 0u) | (v.y != 0 ? 2u : 0u) |
                             (v.z != 0 ? 4u : 0u) | (v.w != 0 ? 8u : 0u);
                unsigned b  = n   | ((unsigned)__shfl_xor((int)n,   1, 64) << 4);
                unsigned hw = b   | ((unsigned)__shfl_xor((int)b,   2, 64) << 8);
                unsigned d  = hw  | ((unsigned)__shfl_xor((int)hw,  4, 64) << 16);
                if ((lane & 7) == 0) drow[(p4 * 4 + k) * 8 + (lane >> 3)] = d;
            }
        }
        return;
    }

    // ---- GEMM block ----
    ((float4*)out)[bid * 256 + t] = make_float4(0.f, 0.f, 0.f, 0.f);

    const int hd = bid >> 6;
    const int n0 = (bid & 63) * 64;
    const int c0 = hd * 64;

    {   // stage x rows n0..n0+63 as bf16
        const float4* xsrc = (const float4*)(x + (size_t)n0 * FIN);
        #pragma unroll
        for (int it = 0; it < 16; ++it) {
            const int fi = it * 256 + t;
            const float4 v = xsrc[fi];
            short4 o;
            o.x = f2bf(v.x); o.y = f2bf(v.y); o.z = f2bf(v.z); o.w = f2bf(v.w);
            *(short4*)&xs[fi >> 6][(fi & 63) * 4] = o;
        }
    }
    {   // stage W^T column slice
        const int c  = t & 63;
        const int k4 = (t >> 6) * 4;
        #pragma unroll
        for (int it = 0; it < 16; ++it) {
            const int k = it * 16 + k4;
            short4 pk;
            pk.x = f2bf(W[(k + 0) * CC + c0 + c]);
            pk.y = f2bf(W[(k + 1) * CC + c0 + c]);
            pk.z = f2bf(W[(k + 2) * CC + c0 + c]);
            pk.w = f2bf(W[(k + 3) * CC + c0 + c]);
            *(short4*)&wts[c][k] = pk;
        }
    }
    __syncthreads();

    const int m = lane & 15;
    const int q = lane >> 4;

    f32x4 acc[4];
    #pragma unroll
    for (int ct = 0; ct < 4; ++ct) acc[ct] = (f32x4){0.f, 0.f, 0.f, 0.f};

    #pragma unroll
    for (int ks = 0; ks < 8; ++ks) {
        const bf16x8 af = *(const bf16x8*)&xs[w * 16 + m][ks * 32 + q * 8];
        #pragma unroll
        for (int ct = 0; ct < 4; ++ct) {
            const bf16x8 bf_ = *(const bf16x8*)&wts[ct * 16 + m][ks * 32 + q * 8];
            acc[ct] = __builtin_amdgcn_mfma_f32_16x16x32_bf16(af, bf_, acc[ct], 0, 0, 0);
        }
    }

    // e1/e2 from fp32 acc (C layout: row=q*4+r, col=ct*16+m)
    const float a1v[4] = {a[m], a[16 + m], a[32 + m], a[48 + m]};
    const float a2v[4] = {a[64 + m], a[80 + m], a[96 + m], a[112 + m]};
    #pragma unroll
    for (int r = 0; r < 4; ++r) {
        float s1 = 0.f, s2 = 0.f;
        #pragma unroll
        for (int ct = 0; ct < 4; ++ct) {
            s1 = fmaf(acc[ct][r], a1v[ct], s1);
            s2 = fmaf(acc[ct][r], a2v[ct], s2);
        }
        #pragma unroll
        for (int sh = 1; sh < 16; sh <<= 1) {
            s1 += __shfl_xor(s1, sh, 64);
            s2 += __shfl_xor(s2, sh, 64);
        }
        if (m == 0) {
            const int n = n0 + w * 16 + q * 4 + r;
            e1T[hd * N + n] = s1;
            e2T[hd * N + n] = s2;
        }
    }

    // transpose h tile to hbuf[c][n-local]
    #pragma unroll
    for (int ct = 0; ct < 4; ++ct)
        #pragma unroll
        for (int r = 0; r < 4; ++r)
            hbuf[ct * 16 + m][w * 16 + q * 4 + r] = f2bf(acc[ct][r]);
    __syncthreads();

    // write hF in fragment order: frag(jc, ft) lane lp holds
    // h[f=ft*16+(lp&15)][j = jc*32 + (lp>>4)*8 + 0..7]
    {
        const int lp = t & 63;
        const int ft = t >> 6;
        const int mm = lp & 15;
        const int qq = lp >> 4;
        #pragma unroll
        for (int c2 = 0; c2 < 2; ++c2) {
            const bf16x8 hv = *(const bf16x8*)&hbuf[ft * 16 + mm][c2 * 32 + qq * 8];
            const size_t jc = (size_t)(n0 >> 5) + c2;
            *(bf16x8*)(hF + ((((size_t)hd * 128 + jc) * 4 + ft) * 64 + lp) * 8) = hv;
        }
    }
}

// Kernel 2: masked-softmax aggregation via MFMA, 32 i-rows per block
// (2 A-frags share each B-frag -> hF L2 traffic halved). One head per
// block; 8 waves = 8 j-stripes (Z completes in-block). Grid 512 = 2/CU.
__global__ __launch_bounds__(512, 4) void gat_k2(const short* __restrict__ hF,
                                                 const unsigned* __restrict__ adjb,
                                                 const float* __restrict__ e1T,
                                                 const float* __restrict__ e2T,
                                                 float* __restrict__ out) {
    __shared__ float obuf[32][64];            //  8 KB
    __shared__ float zbuf[8][32];             //  1 KB
    __shared__ __align__(16) float e2lds[N];  // 16 KB
    __shared__ unsigned adjlds[32 * 129];     // 16.5 KB (129-dw pitch, odd)
    const int t    = threadIdx.x;
    const int lane = t & 63;
    const int g    = t >> 6;
    const int bid  = blockIdx.x;
    const int hd   = (bid >> 3) & 3;
    const int it   = (bid & 7) | ((bid >> 5) << 3);   // XCD-affine i-tile
    const int i0   = it * 32;
    const int m    = lane & 15;
    const int q    = lane >> 4;

    {   // zero numerator
        float* ob = &obuf[0][0];
        #pragma unroll
        for (int r = 0; r < 4; ++r) ob[t + r * 512] = 0.f;
    }
    {   // stage e2 (this head, all j)
        const float4* src = (const float4*)(e2T + (size_t)hd * N);
        float4* dst = (float4*)e2lds;
        dst[t] = src[t]; dst[t + 512] = src[t + 512];
    }
    {   // stage adj bits for 32 i-rows
        const unsigned* src = adjb + (size_t)i0 * 128;
        #pragma unroll
        for (int r = 0; r < 8; ++r) {
            const int idx = t + r * 512;
            adjlds[(idx >> 7) * 129 + (idx & 127)] = src[idx];
        }
    }
    __syncthreads();

    const float e1a = e1T[hd * N + i0 + m];
    const float e1b = e1T[hd * N + i0 + 16 + m];

    f32x4 accf[4], accg[4];
    #pragma unroll
    for (int ft = 0; ft < 4; ++ft) {
        accf[ft] = (f32x4){0.f, 0.f, 0.f, 0.f};
        accg[ft] = (f32x4){0.f, 0.f, 0.f, 0.f};
    }
    float zacc0 = 0.f, zacc1 = 0.f;

    const short* hbase = hF + (((size_t)hd * 128 + g) * 4 * 64 + lane) * 8;
    const unsigned char* abyte0 = ((const unsigned char*)adjlds) + m * 516 + g * 4 + q;
    const unsigned char* abyte1 = abyte0 + 16 * 516;

    for (int step = 0; step < 16; ++step) {
        const short* hstep = hbase + (size_t)step * 16384;   // 8 chunks * 2048
        const bf16x8 b0 = *(const bf16x8*)(hstep);
        const bf16x8 b1 = *(const bf16x8*)(hstep + 512);
        const bf16x8 b2 = *(const bf16x8*)(hstep + 1024);
        const bf16x8 b3 = *(const bf16x8*)(hstep + 1536);

        const int jbase = g * 32 + step * 256 + q * 8;
        const float4 ce0 = *(const float4*)&e2lds[jbase];
        const float4 ce1 = *(const float4*)&e2lds[jbase + 4];
        const unsigned bits0 = (unsigned)abyte0[step * 32];
        const unsigned bits1 = (unsigned)abyte1[step * 32];

        const float ev[8] = {ce0.x, ce0.y, ce0.z, ce0.w, ce1.x, ce1.y, ce1.z, ce1.w};
        bf16x8 af0, af1;
        #pragma unroll
        for (int jj = 0; jj < 8; ++jj) {
            float ea = e1a + ev[jj];
            float eb = e1b + ev[jj];
            ea = fmaxf(ea, 0.2f * ea);
            eb = fmaxf(eb, 0.2f * eb);
            const float wa = ((bits0 >> jj) & 1u) ? __expf(ea) : 0.f;
            const float wb = ((bits1 >> jj) & 1u) ? __expf(eb) : 0.f;
            zacc0 += wa; zacc1 += wb;
            af0[jj] = f2bf(wa);
            af1[jj] = f2bf(wb);
        }

        accf[0] = __builtin_amdgcn_mfma_f32_16x16x32_bf16(af0, b0, accf[0], 0, 0, 0);
        accg[0] = __builtin_amdgcn_mfma_f32_16x16x32_bf16(af1, b0, accg[0], 0, 0, 0);
        accf[1] = __builtin_amdgcn_mfma_f32_16x16x32_bf16(af0, b1, accf[1], 0, 0, 0);
        accg[1] = __builtin_amdgcn_mfma_f32_16x16x32_bf16(af1, b1, accg[1], 0, 0, 0);
        accf[2] = __builtin_amdgcn_mfma_f32_16x16x32_bf16(af0, b2, accf[2], 0, 0, 0);
        accg[2] = __builtin_amdgcn_mfma_f32_16x16x32_bf16(af1, b2, accg[2], 0, 0, 0);
        accf[3] = __builtin_amdgcn_mfma_f32_16x16x32_bf16(af0, b3, accf[3], 0, 0, 0);
        accg[3] = __builtin_amdgcn_mfma_f32_16x16x32_bf16(af1, b3, accg[3], 0, 0, 0);
    }

    // Z: stripe partial per row
    zacc0 += __shfl_xor(zacc0, 16, 64);
    zacc0 += __shfl_xor(zacc0, 32, 64);
    zacc1 += __shfl_xor(zacc1, 16, 64);
    zacc1 += __shfl_xor(zacc1, 32, 64);
    if (lane < 16) {
        zbuf[g][lane]      = zacc0;
        zbuf[g][16 + lane] = zacc1;
    }

    // numerator: C layout row=q*4+r, col=ft*16+m
    #pragma unroll
    for (int ft = 0; ft < 4; ++ft)
        #pragma unroll
        for (int r = 0; r < 4; ++r) {
            atomicAdd(&obuf[q * 4 + r][ft * 16 + m], accf[ft][r]);
            atomicAdd(&obuf[16 + q * 4 + r][ft * 16 + m], accg[ft][r]);
        }
    __syncthreads();

    #pragma unroll
    for (int rep = 0; rep < 4; ++rep) {
        const int idx = t + rep * 512;
        const int ii  = idx >> 6;     // 0..31
        const int ff  = idx & 63;
        float Z = 0.f;
        #pragma unroll
        for (int gg = 0; gg < 8; ++gg) Z += zbuf[gg][ii];
        atomicAdd(&out[(size_t)(i0 + ii) * FOUT + ff], 0.25f * obuf[ii][ff] / Z);
    }
}

extern "C" void kernel_launch(void* const* d_in, const int* in_sizes, int n_in,
                              void* d_out, int out_size, void* d_ws, size_t ws_size,
                              hipStream_t stream) {
    const float* x   = (const float*)d_in[0];
    const int*   adj = (const int*)d_in[1];
    const float* W   = (const float*)d_in[2];
    const float* a   = (const float*)d_in[3];
    float* out = (float*)d_out;

    short*    hF   = (short*)d_ws;                           // 2 MB
    float*    e1T  = (float*)(hF + (size_t)HEADS * FOUT * N);
    float*    e2T  = e1T + (size_t)HEADS * N;
    unsigned* adjb = (unsigned*)(e2T + (size_t)HEADS * N);   // 2 MB

    gat_k1<<<1280, 256, 0, stream>>>(x, W, a, adj, hF, e1T, e2T, adjb, out);
    gat_k2<<<512, 512, 0, stream>>>(hF, adjb, e1T, e2T, out);
}